// Round 1
// 186.769 us; speedup vs baseline: 1.0082x; 1.0082x over previous
//
#include <hip/hip_runtime.h>
#include <cmath>

// ---------------- problem constants ----------------
#define M_ROWS   11520      // 2*5760
#define DIM      512
#define HID      1960
#define HIDP     2048       // padded HID (zeros)
#define KP2      1984       // GEMM2 K-loop bound: 31*64 >= HID, cols [1960,1984) are zero
#define OH       20
#define OW       36
#define LVEC     720        // OH*OW
#define NCH      40         // HID/49
#define BPRIME   16         // M_ROWS / LVEC
#define HP       66         // 60 + 2*3
#define WP       114        // 108 + 2*3

typedef unsigned short u16;
typedef __bf16 bf16x8 __attribute__((ext_vector_type(8)));
typedef float  f32x4  __attribute__((ext_vector_type(4)));

__device__ __forceinline__ u16 f2bf(float f) {
    unsigned u = __float_as_uint(f);
    u += 0x7fffu + ((u >> 16) & 1u);   // RNE
    return (u16)(u >> 16);
}
__device__ __forceinline__ float bf2f(u16 h) {
    return __uint_as_float(((unsigned)h) << 16);
}

__device__ __forceinline__ void gload_lds16(const void* g, void* l) {
    __builtin_amdgcn_global_load_lds(
        (const __attribute__((address_space(1))) void*)g,
        (__attribute__((address_space(3))) void*)l, 16, 0, 0);
}

// ---------------- fused fp32 -> bf16 converts + g2 pad-zeroing (one dispatch) ----------------
// blocks [0,5760): x; [5760,6784): W1 pad-rows; [6784,7808): W2 pad-cols;
// [7808,8078): zero g2 cols [1960,1984) (read by GEMM2's K-trim loop).
#define CVT_XB   5760
#define CVT_W1B  1024
#define CVT_W2B  1024
#define CVT_Z    270       // 11520 rows * 24 cols / (256*4)
__global__ __launch_bounds__(256) void cvt_all(const float* __restrict__ x,
                                               const float* __restrict__ W1,
                                               const float* __restrict__ W2,
                                               u16* __restrict__ xb,
                                               u16* __restrict__ W1b,
                                               u16* __restrict__ W2b,
                                               u16* __restrict__ g2) {
    const int b = blockIdx.x;
    const int tid = threadIdx.x;
    ushort4 o;
    if (b < CVT_XB) {
        int i = (b * 256 + tid) * 4;
        float4 v = *(const float4*)(x + i);
        o.x = f2bf(v.x); o.y = f2bf(v.y); o.z = f2bf(v.z); o.w = f2bf(v.w);
        *(ushort4*)(xb + i) = o;
    } else if (b < CVT_XB + CVT_W1B) {
        int i = ((b - CVT_XB) * 256 + tid) * 4;      // over 2048*512
        if (i < HID * DIM) {
            float4 v = *(const float4*)(W1 + i);
            o.x = f2bf(v.x); o.y = f2bf(v.y); o.z = f2bf(v.z); o.w = f2bf(v.w);
        } else {
            o.x = o.y = o.z = o.w = 0;
        }
        *(ushort4*)(W1b + i) = o;
    } else if (b < CVT_XB + CVT_W1B + CVT_W2B) {
        int i = ((b - CVT_XB - CVT_W1B) * 256 + tid) * 4;   // over 512*2048
        int d = i / HIDP, c = i - d * HIDP;
        if (c < HID) {
            float4 v = *(const float4*)(W2 + (size_t)d * HID + c);
            o.x = f2bf(v.x); o.y = f2bf(v.y); o.z = f2bf(v.z); o.w = f2bf(v.w);
        } else {
            o.x = o.y = o.z = o.w = 0;
        }
        *(ushort4*)(W2b + i) = o;
    } else {
        int i = ((b - CVT_XB - CVT_W1B - CVT_W2B) * 256 + tid) * 4;  // over 11520*24
        int row = i / 24, c = i - row * 24;
        o.x = o.y = o.z = o.w = 0;
        *(ushort4*)(g2 + (size_t)row * HIDP + HID + c) = o;
    }
}

// ---------------- bf16 NT-GEMM: C[m,n] = sum_k A[m,k]*B[n,k] + bias[n] ----------------
// 128(M) x BN(N) tile, BK=64, 512 threads = 8 waves (4 M x 2 N), each wave
// 32 x BN/2 via mfma_f32_16x16x32_bf16. LDS staged with global_load_lds
// width 16; XOR swizzle applied on the GLOBAL side (LDS dest is
// wave-uniform+lane*16) so ds_read_b128 is bank-conflict-free.
//
// XCD-locality block swizzle: hardware assigns XCD = blockIdx % 8 (round-robin).
// v = (blockIdx&7)*(NB/8) + (blockIdx>>3) gives each XCD a contiguous strip of
// bm values x all bn -> A-panels are fetched into ONE per-XCD L2 (not 8), and
// the B matrix (2 MB) stays L2-resident. Requires gridDim.x % 8 == 0.
template <int OUT_BF16, int BN>
__global__ __launch_bounds__(512) void gemm_bt(const u16* __restrict__ A,
                                               const u16* __restrict__ B,
                                               const float* __restrict__ bias,
                                               int biasN, void* __restrict__ Cout,
                                               int N, int K, int ldk) {
    constexpr int WN = BN / 2;       // wave N extent
    constexpr int NU = WN / 16;      // acc tiles along N (4 or 2)
    constexpr int BCH = BN * 8;      // B-tile 16B chunks (1024 or 512)

    __shared__ u16 sA[128 * 64];
    __shared__ u16 sB[BN * 64];

    const int tid  = threadIdx.x;
    const int ntn  = N / BN;
    const int NB   = gridDim.x;
    const int v    = (blockIdx.x & 7) * (NB >> 3) + (blockIdx.x >> 3);
    const int bm   = v / ntn;
    const int bn   = v - bm * ntn;
    const int lane = tid & 63;
    const int wv   = tid >> 6;       // 0..7
    const int wm   = (wv >> 1) * 32; // 4 wave-rows of 32
    const int wn   = (wv & 1) * WN;  // 2 wave-cols
    const int r    = lane & 15;
    const int quad = lane >> 4;

    const size_t Arow0 = (size_t)bm * 128 * ldk;
    const size_t Brow0 = (size_t)bn * BN * ldk;

    f32x4 acc[2][NU] = {};

    for (int kt = 0; kt < K; kt += 64) {
        __syncthreads();
#pragma unroll
        for (int i = 0; i < 2; i++) {          // A: 1024 chunks / 512 threads
            int e   = i * 512 + tid;
            int row = e >> 3;
            int cp  = e & 7;
            int cg  = cp ^ (row & 7);
            gload_lds16(A + Arow0 + (size_t)row * ldk + kt + cg * 8, (char*)sA + e * 16);
        }
#pragma unroll
        for (int i = 0; i < BCH / 512; i++) {  // B: BCH chunks / 512 threads
            int e   = i * 512 + tid;
            int row = e >> 3;
            int cp  = e & 7;
            int cg  = cp ^ (row & 7);
            gload_lds16(B + Brow0 + (size_t)row * ldk + kt + cg * 8, (char*)sB + e * 16);
        }
        __syncthreads();
#pragma unroll
        for (int kk = 0; kk < 2; kk++) {
            bf16x8 af[2], bg[NU];
#pragma unroll
            for (int t = 0; t < 2; t++) {
                int row = wm + t * 16 + r;
                int c   = (kk * 4 + quad) ^ (row & 7);
                af[t] = *(const bf16x8*)(sA + row * 64 + c * 8);
            }
#pragma unroll
            for (int u = 0; u < NU; u++) {
                int row = wn + u * 16 + r;
                int c   = (kk * 4 + quad) ^ (row & 7);
                bg[u] = *(const bf16x8*)(sB + row * 64 + c * 8);
            }
#pragma unroll
            for (int t = 0; t < 2; t++)
#pragma unroll
                for (int u = 0; u < NU; u++)
                    acc[t][u] = __builtin_amdgcn_mfma_f32_16x16x32_bf16(
                        af[t], bg[u], acc[t][u], 0, 0, 0);
        }
    }

    // epilogue: C/D layout col = lane&15 (n), row = quad*4+q (m)
    const int gm0 = bm * 128 + wm;
    const int gn0 = bn * BN + wn;
#pragma unroll
    for (int u = 0; u < NU; u++) {
        int gn = gn0 + u * 16 + r;
        float bv = (gn < biasN) ? bias[gn] : 0.0f;
#pragma unroll
        for (int t = 0; t < 2; t++) {
            int gm = gm0 + t * 16 + quad * 4;
#pragma unroll
            for (int q = 0; q < 4; q++) {
                float v2 = acc[t][u][q] + bv;
                if (OUT_BF16)
                    ((u16*)Cout)[(size_t)(gm + q) * N + gn] = f2bf(v2);
                else
                    ((float*)Cout)[(size_t)(gm + q) * N + gn] = v2;
            }
        }
    }
}

// ---------------- mid: fold + normalize + crop + GELU + unfold, fully fused ----------------
// One block per (b', ch, half-oy s, half-ox xh). Grid = 16*40*2*2 = 2560,
// ~31 KB LDS -> 4 blocks/CU (wave-slot capped, 32 waves/CU steady state;
// old half-only split was 52 KB -> 3/CU with a 3+2 round tail at 39% occ).
//
// Block owns oy rows [10s,10s+10) x ox cols [18xh,18xh+18). Needs G pixel
// rows [30s,30s+34) x px cols [54xh, 54xh+58), which depend on h oy-rows
// [8s,8s+12) x ox-cols [16xh, 16xh+20).
//
// phase0: 12x20 h-rows -> LDS via global_load_lds WIDTH-16: channel base
//         rounded down to 16B (c0f = c0 & ~7, koff = c0 & 7 <= 7), so each
//         49-ch row fits koff+49 <= 56 u16 = exactly 7x16B chunks (vs the
//         old 25x 4B DMAs/row). Index math via magic-mul (no div).
// phase1: 34 G rows x 58 local cols into sG (column-strip threading, hoisted
//         kx terms, exact gelu once per pixel). G never touches global.
// phase2: unfold sG -> g2; all indices from j via magic-mul constants
//         (validated over their exact ranges), no LDS LUTs.
__global__ __launch_bounds__(512) void mid_fused(const u16* __restrict__ hg,
                                                 u16* __restrict__ g2) {
    __shared__ u16 sh[12 * 20 * 56];   // 13440 u16 = 26880 B
    __shared__ u16 sG[34 * 58];        //  1972 u16 =  3944 B

    const int b   = blockIdx.x;
    const int bp  = b / (NCH * 4);
    const int rr  = b - bp * (NCH * 4);
    const int ch  = rr >> 2;
    const int s   = (rr >> 1) & 1;
    const int xh  = rr & 1;
    const int o0  = s * 10;            // first owned oy
    const int lo  = s * 8;             // first loaded oy
    const int ox0 = xh * 16;           // first loaded ox
    const int n0  = bp * LVEC;
    const int c0  = ch * 49;
    const int c0f = c0 & ~7;           // 16B-aligned channel base
    const int koff = c0 & 7;           // 0..7 (koff + 49 <= 56)
    const int tid = threadIdx.x;

    // phase 0: 12 oy-rows x 20 ox-cols x 7 chunks of 16B, DMA'd to LDS.
    // task t -> row r = t/7 (magic *74899>>19, exact for t<1680), chunk c;
    // r -> (loy = r/20 via *3277>>16 exact for r<240, oxl).
    {
        const char* hb = (const char*)(hg + (size_t)(n0 + lo * 36 + ox0) * HIDP + c0f);
        for (int t = tid; t < 12 * 20 * 7; t += 512) {
            int r   = (int)(((unsigned)t * 74899u) >> 19);
            int c   = t - r * 7;
            int loy = (int)(((unsigned)r * 3277u) >> 16);
            int oxl = r - 20 * loy;
            gload_lds16(hb + (size_t)(loy * 36 + oxl) * (HIDP * 2) + c * 16,
                        (char*)sh + t * 16);
        }
    }
    __syncthreads();

    // phase 1: G rows [3*o0, 3*o0+34) x local px [0,58) -> sG
    const int pxl = tid & 63;
    const int rg  = tid >> 6;          // 0..7, wave-uniform
    if (pxl < 58) {
        const int  pxg  = pxl + 54 * xh;              // global px
        const bool pxin = (pxg >= 3) && (pxg <= 110);
        const int  kx0  = pxg % 3;
        int  ct[3];
        bool vx[3];
        int  cx = 0;
#pragma unroll
        for (int dx = 0; dx < 3; dx++) {
            int kx = kx0 + 3 * dx, rx = pxg - kx;
            bool ok = pxin && (kx <= 6) && (rx >= 0) && (rx <= 105);
            vx[dx] = ok;
            ct[dx] = ok ? ((rx / 3) - ox0) * 56 + kx : 0;
            cx += ok ? 1 : 0;
        }
        const float fcx = (cx == 3) ? (1.0f / 3.0f) : ((cx == 2) ? 0.5f : 1.0f);

        for (int pr = rg; pr < 34; pr += 8) {
            int py = 3 * o0 + pr;      // wave-uniform
            float val = 0.0f;
            if (pxin && py >= 3 && py <= 62) {
                int ky0 = py % 3;
                float sum = 0.0f;
                int cy = 0;
#pragma unroll
                for (int dy = 0; dy < 3; dy++) {
                    int ky = ky0 + 3 * dy, ry = py - ky;   // uniform
                    if (ky <= 6 && ry >= 0 && ry <= 57) {  // uniform branch
                        int rt = (ry / 3 - lo) * (20 * 56) + ky * 7 + koff;
                        cy++;
                        float v0 = bf2f(sh[rt + ct[0]]);
                        float v1 = bf2f(sh[rt + ct[1]]);
                        float v2 = bf2f(sh[rt + ct[2]]);
                        sum += vx[0] ? v0 : 0.0f;
                        sum += vx[1] ? v1 : 0.0f;
                        sum += vx[2] ? v2 : 0.0f;
                    }
                }
                float fcy = (cy == 3) ? (1.0f / 3.0f) : ((cy == 2) ? 0.5f : 1.0f);
                float m = sum * fcx * fcy;
                val = 0.5f * m * (1.0f + erff(m * 0.70710678118654752f));  // exact gelu
            }
            sG[pr * 58 + pxl] = f2bf(val);
        }
    }
    __syncthreads();

    // phase 2: unfold sG -> g2. Task j over 10 oy x 18 ox x 49 k.
    //   l2 = j/49  (*42800>>21, exact for j<8820), k = j%49
    //   oy = l2/18 (*57>>10, exact for l2<190),    ox = l2%18
    //   ky = k/7   (*37>>8, exact for k<56),       kx = k%7
    //   sG idx = (3oy+ky)*58 + 3ox+kx  (pxl = 3*ox_local + kx, xh cancels)
    {
        u16* g2row = g2 + (size_t)(n0 + o0 * 36 + 18 * xh) * HIDP + c0;
        for (int j = tid; j < 10 * 18 * 49; j += 512) {
            int l2 = (int)(((unsigned)j * 42800u) >> 21);
            int k  = j - l2 * 49;
            int oy = (int)(((unsigned)l2 * 57u) >> 10);
            int ox = l2 - 18 * oy;
            int ky = (int)(((unsigned)k * 37u) >> 8);
            int kx = k - 7 * ky;
            g2row[(size_t)(oy * 36 + ox) * HIDP + k] =
                sG[(3 * oy + ky) * 58 + 3 * ox + kx];
        }
    }
}

// ---------------- launch ----------------
extern "C" void kernel_launch(void* const* d_in, const int* in_sizes, int n_in,
                              void* d_out, int out_size, void* d_ws, size_t ws_size,
                              hipStream_t stream) {
    (void)in_sizes; (void)n_in; (void)out_size; (void)ws_size;
    const float* x  = (const float*)d_in[0];
    const float* W1 = (const float*)d_in[1];
    const float* b1 = (const float*)d_in[2];
    const float* W2 = (const float*)d_in[3];
    const float* b2 = (const float*)d_in[4];
    float* out = (float*)d_out;

    char* ws = (char*)d_ws;
    u16* xb  = (u16*)(ws);                       // 11520*512*2  = 11,796,480
    u16* W1b = (u16*)(ws + 11796480);            // 2048*512*2   =  2,097,152
    u16* W2b = (u16*)(ws + 13893632);            // 512*2048*2   =  2,097,152
    u16* hg  = (u16*)(ws + 15990784);            // 11520*2048*2 = 47,185,920
    u16* g2  = (u16*)(ws + 63176704);            // 11520*2048*2 = 47,185,920 (total 110 MB)

    // converts + g2 pad-zeroing (single dispatch)
    cvt_all<<<CVT_XB + CVT_W1B + CVT_W2B + CVT_Z, 256, 0, stream>>>(
        x, W1, W2, xb, W1b, W2b, g2);

    // GEMM1: h = x @ W1^T + b1  -> bf16 (11520 x 2048, cols >=1960 are zero)
    gemm_bt<1, 128><<<(M_ROWS / 128) * (HIDP / 128), 512, 0, stream>>>(
        xb, W1b, b1, HID, (void*)hg, HIDP, DIM, DIM);

    // middle: fold/normalize/gelu/unfold fused, hg -> g2 (G stays in LDS)
    mid_fused<<<BPRIME * NCH * 4, 512, 0, stream>>>(hg, g2);

    // GEMM2: out = g2 @ W2^T + b2 -> fp32 (11520 x 512), 128x64 tiles, K-loop
    // trimmed to 1984 (g2 cols [1960,1984) zero-filled by cvt_all).
    gemm_bt<0, 64><<<(M_ROWS / 128) * (DIM / 64), 512, 0, stream>>>(
        g2, W2b, b2, DIM, (void*)out, DIM, KP2, HIDP);
}